// Round 10
// baseline (213.576 us; speedup 1.0000x reference)
//
#include <hip/hip_runtime.h>
#include <cstdint>

static constexpr int DD = 256;   // feature dim (fixed by problem)
static constexpr int SNB = 64;   // scan blocks per array

typedef unsigned short ushort_t;
typedef __attribute__((ext_vector_type(8))) short short8v;   // 8 bf16 (4 VGPRs)
typedef __attribute__((ext_vector_type(4))) float f32x4;

static __device__ inline ushort_t f2bf(float f) {     // RNE f32->bf16 (no NaN in data)
  uint32_t u = __builtin_bit_cast(uint32_t, f);
  uint32_t r = (u + 0x7fffu + ((u >> 16) & 1u)) >> 16;
  return (ushort_t)r;
}
static __device__ inline float bf2f(ushort_t u) {
  return __builtin_bit_cast(float, (uint32_t)u << 16);
}
// unpack int4 (8 packed bf16) and accumulate into a[0..7] (static indices only)
static __device__ inline void addbf8(float* a, int4 x) {
  uint32_t ux = (uint32_t)x.x, uy = (uint32_t)x.y;
  uint32_t uz = (uint32_t)x.z, uw = (uint32_t)x.w;
  a[0] += __builtin_bit_cast(float, ux << 16);
  a[1] += __builtin_bit_cast(float, ux & 0xFFFF0000u);
  a[2] += __builtin_bit_cast(float, uy << 16);
  a[3] += __builtin_bit_cast(float, uy & 0xFFFF0000u);
  a[4] += __builtin_bit_cast(float, uz << 16);
  a[5] += __builtin_bit_cast(float, uz & 0xFFFF0000u);
  a[6] += __builtin_bit_cast(float, uw << 16);
  a[7] += __builtin_bit_cast(float, uw & 0xFFFF0000u);
}

// ---------------- fused prep: Wt convert + zero rows | X->bf16 | count ----------------
// blocks [0,256): Wt[col][k]=bf16(W[k][col]); block 0 zeroes Xe row M & Xbf row N.
// blocks [256, 256+xb): xcvt (X -> Xbf in d_out scratch).
// blocks [256+xb, ...): count (atomics into cntV/cntE; memset precedes on stream).

__global__ __launch_bounds__(256) void k_prep(const float* __restrict__ W,
                                              ushort_t* __restrict__ Wt,
                                              ushort_t* __restrict__ XeZ,
                                              ushort_t* __restrict__ XbfZ,
                                              const float* __restrict__ X,
                                              ushort_t* __restrict__ Xbf, int total4,
                                              const int* __restrict__ vertex,
                                              const int* __restrict__ edges,
                                              int* __restrict__ cntV,
                                              int* __restrict__ cntE, int nnz,
                                              int xb) {
  int b = blockIdx.x;
  if (b < 256) {
    int t = b * 256 + threadIdx.x;
    int k = t >> 8, c = t & 255;
    Wt[c * 256 + k] = f2bf(W[t]);
    if (b == 0) {
      int4 z = make_int4(0, 0, 0, 0);
      if (threadIdx.x < 32)       reinterpret_cast<int4*>(XeZ)[threadIdx.x] = z;
      else if (threadIdx.x < 64)  reinterpret_cast<int4*>(XbfZ)[threadIdx.x - 32] = z;
    }
  } else if (b < 256 + xb) {
    int i = (b - 256) * 256 + threadIdx.x;
    if (i < total4) {
      float4 v = reinterpret_cast<const float4*>(X)[i];
      ushort4 r;
      r.x = f2bf(v.x); r.y = f2bf(v.y); r.z = f2bf(v.z); r.w = f2bf(v.w);
      reinterpret_cast<ushort4*>(Xbf)[i] = r;
    }
  } else {
    int i = (b - 256 - xb) * 256 + threadIdx.x;
    if (i < nnz) {
      atomicAdd(&cntV[vertex[i]], 1);
      atomicAdd(&cntE[edges[i]], 1);
    }
  }
}

__device__ inline int wave_incl_scan(int v, int lane) {
  #pragma unroll
  for (int o = 1; o < 64; o <<= 1) {
    int u = __shfl_up(v, o);
    if (lane >= o) v += u;
  }
  return v;
}

// Phase 1: per-chunk sums for both arrays. blocks 0..63 -> E, 64..127 -> V.
__global__ __launch_bounds__(256) void k_bsum(const int* __restrict__ cntE,
                                              const int* __restrict__ cntV,
                                              int* __restrict__ bsum, int M, int N) {
  int arr = blockIdx.x >> 6;
  int b = blockIdx.x & 63;
  const int* cnt = arr ? cntV : cntE;
  int n = arr ? N : M;
  int chunk = (((n + SNB - 1) / SNB) + 3) & ~3;
  int lo = b * chunk, hi = min(lo + chunk, n);
  int s = 0;
  for (int i = lo + (int)threadIdx.x; i < hi; i += 256) s += cnt[i];
  #pragma unroll
  for (int o = 32; o; o >>= 1) s += __shfl_down(s, o);
  __shared__ int sh[4];
  if ((threadIdx.x & 63) == 0) sh[threadIdx.x >> 6] = s;
  __syncthreads();
  if (threadIdx.x == 0) bsum[blockIdx.x] = sh[0] + sh[1] + sh[2] + sh[3];
}

// Phase 2: scan the 128 block sums (wave 0 = E, wave 1 = V); write totals.
__global__ __launch_bounds__(128) void k_bscan(const int* __restrict__ bsum,
                                               int* __restrict__ bpre,
                                               int* __restrict__ offsE, int* __restrict__ offsV,
                                               int M, int N) {
  int t = threadIdx.x;
  int lane = t & 63;
  int v = bsum[t];
  int inc = wave_incl_scan(v, lane);
  bpre[t] = inc - v;
  if (lane == 63) {
    if (t < 64) offsE[M] = inc;
    else        offsV[N] = inc;
  }
}

// Phase 3: per-chunk exclusive scan + global base, write offs & cursor (int4).
__global__ __launch_bounds__(256) void k_woffs(const int* __restrict__ cntE,
                                               const int* __restrict__ cntV,
                                               const int* __restrict__ bpre,
                                               int* __restrict__ offsE, int* __restrict__ curE,
                                               int* __restrict__ offsV, int* __restrict__ curV,
                                               int M, int N) {
  int arr = blockIdx.x >> 6;
  int b = blockIdx.x & 63;
  const int* cnt = arr ? cntV : cntE;
  int* offs = arr ? offsV : offsE;
  int* cur  = arr ? curV  : curE;
  int n = arr ? N : M;
  int chunk = (((n + SNB - 1) / SNB) + 3) & ~3;
  int lo = b * chunk, hi = min(lo + chunk, n);
  if (lo >= n) return;
  int base = bpre[blockIdx.x];

  int idx = lo + (int)threadIdx.x * 4;
  int c0 = 0, c1 = 0, c2 = 0, c3 = 0;
  if (idx + 3 < hi) {
    int4 c = *reinterpret_cast<const int4*>(cnt + idx);
    c0 = c.x; c1 = c.y; c2 = c.z; c3 = c.w;
  } else if (idx < hi) {
    c0 = cnt[idx];
    if (idx + 1 < hi) c1 = cnt[idx + 1];
    if (idx + 2 < hi) c2 = cnt[idx + 2];
  }
  int tsum = c0 + c1 + c2 + c3;
  int lane = threadIdx.x & 63, wid = threadIdx.x >> 6;
  int winc = wave_incl_scan(tsum, lane);
  __shared__ int wtot[4];
  if (lane == 63) wtot[wid] = winc;
  __syncthreads();
  int wbase = 0;
  #pragma unroll
  for (int q = 0; q < 4; ++q) wbase += (q < wid) ? wtot[q] : 0;
  int excl = base + wbase + winc - tsum;
  int o0 = excl, o1 = o0 + c0, o2 = o1 + c1, o3 = o2 + c2;
  if (idx + 3 < hi) {
    *reinterpret_cast<int4*>(offs + idx) = make_int4(o0, o1, o2, o3);
    *reinterpret_cast<int4*>(cur + idx)  = make_int4(o0, o1, o2, o3);
  } else if (idx < hi) {
    offs[idx] = o0; cur[idx] = o0;
    if (idx + 1 < hi) { offs[idx + 1] = o1; cur[idx + 1] = o1; }
    if (idx + 2 < hi) { offs[idx + 2] = o2; cur[idx + 2] = o2; }
  }
}

// ushort incidence lists: N=50000, M=20000 both < 65536.
__global__ void k_fill(const int* __restrict__ vertex, const int* __restrict__ edges,
                       int* __restrict__ curE, int* __restrict__ curV,
                       ushort_t* __restrict__ incEv, ushort_t* __restrict__ incVe, int nnz) {
  int i = blockIdx.x * blockDim.x + threadIdx.x;
  if (i < nnz) {
    int v = vertex[i], e = edges[i];
    int pe = atomicAdd(&curE[e], 1);
    incEv[pe] = (ushort_t)v;
    int pv = atomicAdd(&curV[v], 1);
    incVe[pv] = (ushort_t)e;
  }
}

// ---------------- hop 1: mean-aggregate vertices into edges ----------------
// Pair-gather + branch-free masked unroll (dead slots -> zero row).

__global__ void k_hop1(const ushort_t* __restrict__ Xbf, const float* __restrict__ degE,
                       const int* __restrict__ offsE, const ushort_t* __restrict__ incEv,
                       ushort_t* __restrict__ Xe, int M, int zrow) {
  int gw = (blockIdx.x * blockDim.x + threadIdx.x) >> 6;
  int lane = threadIdx.x & 63;
  if (gw >= M) return;
  int half = lane >> 5, sub = lane & 31;
  int s = offsE[gw], t = offsE[gw + 1];
  float acc[8] = {0.f, 0.f, 0.f, 0.f, 0.f, 0.f, 0.f, 0.f};
  const ushort_t* rowbase = Xbf + sub * 8;
  for (int k = s; k < t; k += 8) {
    int4 x[4];
    #pragma unroll
    for (int p = 0; p < 4; ++p) {
      int i0 = k + 2 * p + half;
      int j = min(i0, t - 1);
      int idx = (i0 < t) ? (int)incEv[j] : zrow;
      x[p] = *reinterpret_cast<const int4*>(rowbase + (size_t)idx * DD);
    }
    #pragma unroll
    for (int p = 0; p < 4; ++p) addbf8(acc, x[p]);
  }
  #pragma unroll
  for (int j = 0; j < 8; ++j) acc[j] += __shfl_xor(acc[j], 32);
  float scale = degE[gw] / fmaxf((float)(t - s), 1.0f);
  float b0 = half ? acc[4] : acc[0];
  float b1 = half ? acc[5] : acc[1];
  float b2 = half ? acc[6] : acc[2];
  float b3 = half ? acc[7] : acc[3];
  ushort4 r;
  r.x = f2bf(b0 * scale); r.y = f2bf(b1 * scale);
  r.z = f2bf(b2 * scale); r.w = f2bf(b3 * scale);
  *reinterpret_cast<ushort4*>(Xe + (size_t)gw * DD + sub * 8 + half * 4) = r;
}

// ---------------- fused hop2 + GEMM ----------------
// Block = 64 vertices, 512 threads (8 waves). Gather phase: wave w computes
// rows w*8..w*8+7 (sum-aggregate + degV + L2-norm + alpha-mix) and stores the
// row as bf16 into a persistent LDS A-tile (Xi never goes to HBM). GEMM phase:
// 8 waves (2 row x 4 col), wave tile 32x64, B (Wt) staged per 32-k step.
// Epilogue: out = (1-beta)*bf2f(A_lds) + beta*acc, written once.

__global__ __launch_bounds__(512, 4) void k_hop2gemm(
    const ushort_t* __restrict__ Xe, const float* __restrict__ X0,
    const float* __restrict__ degV, const int* __restrict__ offsV,
    const ushort_t* __restrict__ incVe, const float* __restrict__ alpha_p,
    const ushort_t* __restrict__ Wt, const float* __restrict__ beta_p,
    float* __restrict__ out, int N, int zrow) {
  __shared__ ushort_t A_lds[64][264];    // 33 KB, row stride 528 B (16B-aligned)
  __shared__ ushort_t B_lds[256][36];    // 18.4 KB
  const int tid = threadIdx.x;
  const int lane = tid & 63;
  const int wid = tid >> 6;              // 0..7
  const int half = lane >> 5, sub = lane & 31;
  const int row0 = blockIdx.x * 64;
  const float a = alpha_p[0];
  const float oma = 1.0f - a;

  // ---- gather phase ----
  #pragma unroll 1
  for (int r = wid * 8; r < wid * 8 + 8; ++r) {
    int gw = row0 + r;
    int f0 = sub * 8 + half * 4;
    if (gw >= N) {
      *reinterpret_cast<ushort4*>(&A_lds[r][f0]) = make_ushort4(0, 0, 0, 0);
      continue;
    }
    int s = offsV[gw], t = offsV[gw + 1];
    float acc[8] = {0.f, 0.f, 0.f, 0.f, 0.f, 0.f, 0.f, 0.f};
    const ushort_t* rowbase = Xe + sub * 8;
    for (int k = s; k < t; k += 8) {
      int4 x[4];
      #pragma unroll
      for (int p = 0; p < 4; ++p) {
        int i0 = k + 2 * p + half;
        int j = min(i0, t - 1);
        int idx = (i0 < t) ? (int)incVe[j] : zrow;
        x[p] = *reinterpret_cast<const int4*>(rowbase + (size_t)idx * DD);
      }
      #pragma unroll
      for (int p = 0; p < 4; ++p) addbf8(acc, x[p]);
    }
    #pragma unroll
    for (int j = 0; j < 8; ++j) acc[j] += __shfl_xor(acc[j], 32);
    float dv = degV[gw];
    float b0 = (half ? acc[4] : acc[0]) * dv;
    float b1 = (half ? acc[5] : acc[1]) * dv;
    float b2 = (half ? acc[6] : acc[2]) * dv;
    float b3 = (half ? acc[7] : acc[3]) * dv;
    float ss = b0 * b0 + b1 * b1 + b2 * b2 + b3 * b3;
    #pragma unroll
    for (int o = 1; o < 64; o <<= 1) ss += __shfl_xor(ss, o);
    float norm = sqrtf(ss);
    float scl = (norm > 0.f) ? (1.0f / norm) : 0.f;
    float4 x0 = *reinterpret_cast<const float4*>(X0 + (size_t)gw * DD + f0);
    ushort4 w;
    w.x = f2bf(oma * (b0 * scl) + a * x0.x);
    w.y = f2bf(oma * (b1 * scl) + a * x0.y);
    w.z = f2bf(oma * (b2 * scl) + a * x0.z);
    w.w = f2bf(oma * (b3 * scl) + a * x0.w);
    *reinterpret_cast<ushort4*>(&A_lds[r][f0]) = w;
  }
  __syncthreads();

  // ---- GEMM phase ----
  const int wr = wid >> 2, wc = wid & 3;
  const int l15 = lane & 15, l4 = lane >> 4;
  const int bcol = tid >> 1, bt2 = tid & 1;
  f32x4 acc2[2][4];
  #pragma unroll
  for (int m = 0; m < 2; ++m)
    #pragma unroll
    for (int n = 0; n < 4; ++n) acc2[m][n] = (f32x4){0.f, 0.f, 0.f, 0.f};

  for (int k0 = 0; k0 < 256; k0 += 32) {
    const ushort_t* src = Wt + (size_t)bcol * 256 + k0 + bt2 * 16;
    *reinterpret_cast<int4*>(&B_lds[bcol][bt2 * 16 + 0]) = *reinterpret_cast<const int4*>(src + 0);
    *reinterpret_cast<int4*>(&B_lds[bcol][bt2 * 16 + 8]) = *reinterpret_cast<const int4*>(src + 8);
    __syncthreads();
    short8v av[2], bv[4];
    #pragma unroll
    for (int m = 0; m < 2; ++m)
      av[m] = *reinterpret_cast<const short8v*>(&A_lds[wr * 32 + m * 16 + l15][k0 + l4 * 8]);
    #pragma unroll
    for (int n = 0; n < 4; ++n)
      bv[n] = *reinterpret_cast<const short8v*>(&B_lds[wc * 64 + n * 16 + l15][l4 * 8]);
    #pragma unroll
    for (int m = 0; m < 2; ++m)
      #pragma unroll
      for (int n = 0; n < 4; ++n)
        acc2[m][n] = __builtin_amdgcn_mfma_f32_16x16x32_bf16(av[m], bv[n], acc2[m][n], 0, 0, 0);
    __syncthreads();
  }

  // ---- epilogue: out = (1-b)*Xi + b*(Xi @ W) ----
  float bta = beta_p[0], ob = 1.0f - bta;
  #pragma unroll
  for (int m = 0; m < 2; ++m) {
    #pragma unroll
    for (int j = 0; j < 4; ++j) {
      int lr = wr * 32 + m * 16 + l4 * 4 + j;
      int gr = row0 + lr;
      if (gr < N) {
        #pragma unroll
        for (int n = 0; n < 4; ++n) {
          int c = wc * 64 + n * 16 + l15;
          out[(size_t)gr * 256 + c] = ob * bf2f(A_lds[lr][c]) + bta * acc2[m][n][j];
        }
      }
    }
  }
}

// ---------------- launch ----------------

extern "C" void kernel_launch(void* const* d_in, const int* in_sizes, int n_in,
                              void* d_out, int out_size, void* d_ws, size_t ws_size,
                              hipStream_t stream) {
  const float* X     = (const float*)d_in[0];
  const float* X0    = (const float*)d_in[1];
  const float* W     = (const float*)d_in[2];
  const float* degV  = (const float*)d_in[3];
  const float* degE  = (const float*)d_in[4];
  const int*   vertex= (const int*)d_in[5];
  const int*   edges = (const int*)d_in[6];
  const float* alpha = (const float*)d_in[7];
  const float* beta  = (const float*)d_in[8];

  const int N   = in_sizes[3];   // degV has N elements
  const int M   = in_sizes[4];   // degE has M elements
  const int NNZ = in_sizes[5];

  auto r4 = [](int x) { return (x + 3) & ~3; };
  const int Mr = r4(M), Nr = r4(N);

  int* w = (int*)d_ws;
  int* cntE  = w; w += Mr;
  int* cntV  = w; w += Nr;        // contiguous with cntE for one memset
  int* offsE = w; w += r4(M + 1);
  int* offsV = w; w += r4(N + 1);
  int* curE  = w; w += Mr;
  int* curV  = w; w += Nr;
  int* bsum  = w; w += 128;
  int* bpre  = w; w += 128;
  ushort_t* incEv16 = (ushort_t*)w; w += (NNZ + 1) / 2;
  ushort_t* incVe16 = (ushort_t*)w; w += (NNZ + 1) / 2;
  uintptr_t p = (uintptr_t)w;
  p = (p + 15) & ~(uintptr_t)15;
  ushort_t* Wt = (ushort_t*)p;           // 256*256 bf16 = 128 KB
  p += (size_t)256 * 256 * sizeof(ushort_t);
  ushort_t* Xe = (ushort_t*)p;           // (M+1)*256 bf16 = 10.24 MB (+1 zero row)
  // total ws ~= 12.8 MB << proven-safe 24.5 MB footprint.

  float*    outF = (float*)d_out;        // final output (written once by fused kernel)
  ushort_t* Xbf  = (ushort_t*)d_out;     // (N+1)*256 bf16 scratch inside d_out:
                                         // written by prep, read by hop1, then
                                         // d_out is overwritten by k_hop2gemm.

  hipMemsetAsync(cntE, 0, (size_t)(Mr + Nr) * sizeof(int), stream);

  int nb = (NNZ + 255) / 256;
  int xb = (N * (DD / 4) + 255) / 256;
  k_prep<<<256 + xb + nb, 256, 0, stream>>>(W, Wt, Xe + (size_t)M * DD,
                                            Xbf + (size_t)N * DD, X, Xbf, N * (DD / 4),
                                            vertex, edges, cntV, cntE, NNZ, xb);
  k_bsum <<<2 * SNB, 256, 0, stream>>>(cntE, cntV, bsum, M, N);
  k_bscan<<<1, 128, 0, stream>>>(bsum, bpre, offsE, offsV, M, N);
  k_woffs<<<2 * SNB, 256, 0, stream>>>(cntE, cntV, bpre, offsE, curE, offsV, curV, M, N);
  k_fill <<<nb, 256, 0, stream>>>(vertex, edges, curE, curV, incEv16, incVe16, NNZ);

  k_hop1<<<(M + 3) / 4, 256, 0, stream>>>(Xbf, degE, offsE, incEv16, Xe, M, N);
  k_hop2gemm<<<(N + 63) / 64, 512, 0, stream>>>(Xe, X0, degV, offsV, incVe16, alpha,
                                                Wt, beta, outF, N, M);
}

// Round 12
// 200.943 us; speedup vs baseline: 1.0629x; 1.0629x over previous
//
#include <hip/hip_runtime.h>
#include <cstdint>

static constexpr int DD = 256;   // feature dim (fixed by problem)
static constexpr int SNB = 64;   // scan blocks per array

typedef unsigned short ushort_t;
typedef __attribute__((ext_vector_type(8))) short short8v;   // 8 bf16 (4 VGPRs)
typedef __attribute__((ext_vector_type(4))) float f32x4;

static __device__ inline ushort_t f2bf(float f) {     // RNE f32->bf16 (no NaN in data)
  uint32_t u = __builtin_bit_cast(uint32_t, f);
  uint32_t r = (u + 0x7fffu + ((u >> 16) & 1u)) >> 16;
  return (ushort_t)r;
}
static __device__ inline float bf2f(ushort_t u) {
  return __builtin_bit_cast(float, (uint32_t)u << 16);
}
// unpack int4 (8 packed bf16) and accumulate into a[0..7] (static indices only)
static __device__ inline void addbf8(float* a, int4 x) {
  uint32_t ux = (uint32_t)x.x, uy = (uint32_t)x.y;
  uint32_t uz = (uint32_t)x.z, uw = (uint32_t)x.w;
  a[0] += __builtin_bit_cast(float, ux << 16);
  a[1] += __builtin_bit_cast(float, ux & 0xFFFF0000u);
  a[2] += __builtin_bit_cast(float, uy << 16);
  a[3] += __builtin_bit_cast(float, uy & 0xFFFF0000u);
  a[4] += __builtin_bit_cast(float, uz << 16);
  a[5] += __builtin_bit_cast(float, uz & 0xFFFF0000u);
  a[6] += __builtin_bit_cast(float, uw << 16);
  a[7] += __builtin_bit_cast(float, uw & 0xFFFF0000u);
}

// ---------------- fused prep: Wt convert + zero rows | X->bf16 | count ----------------
// (proven passing in R10)

__global__ __launch_bounds__(256) void k_prep(const float* __restrict__ W,
                                              ushort_t* __restrict__ Wt,
                                              ushort_t* __restrict__ XeZ,
                                              ushort_t* __restrict__ XbfZ,
                                              const float* __restrict__ X,
                                              ushort_t* __restrict__ Xbf, int total4,
                                              const int* __restrict__ vertex,
                                              const int* __restrict__ edges,
                                              int* __restrict__ cntV,
                                              int* __restrict__ cntE, int nnz,
                                              int xb) {
  int b = blockIdx.x;
  if (b < 256) {
    int t = b * 256 + threadIdx.x;
    int k = t >> 8, c = t & 255;
    Wt[c * 256 + k] = f2bf(W[t]);
    if (b == 0) {
      int4 z = make_int4(0, 0, 0, 0);
      if (threadIdx.x < 32)       reinterpret_cast<int4*>(XeZ)[threadIdx.x] = z;
      else if (threadIdx.x < 64)  reinterpret_cast<int4*>(XbfZ)[threadIdx.x - 32] = z;
    }
  } else if (b < 256 + xb) {
    int i = (b - 256) * 256 + threadIdx.x;
    if (i < total4) {
      float4 v = reinterpret_cast<const float4*>(X)[i];
      ushort4 r;
      r.x = f2bf(v.x); r.y = f2bf(v.y); r.z = f2bf(v.z); r.w = f2bf(v.w);
      reinterpret_cast<ushort4*>(Xbf)[i] = r;
    }
  } else {
    int i = (b - 256 - xb) * 256 + threadIdx.x;
    if (i < nnz) {
      atomicAdd(&cntV[vertex[i]], 1);
      atomicAdd(&cntE[edges[i]], 1);
    }
  }
}

__device__ inline int wave_incl_scan(int v, int lane) {
  #pragma unroll
  for (int o = 1; o < 64; o <<= 1) {
    int u = __shfl_up(v, o);
    if (lane >= o) v += u;
  }
  return v;
}

// Phase 1: per-chunk sums for both arrays. blocks 0..63 -> E, 64..127 -> V.
__global__ __launch_bounds__(256) void k_bsum(const int* __restrict__ cntE,
                                              const int* __restrict__ cntV,
                                              int* __restrict__ bsum, int M, int N) {
  int arr = blockIdx.x >> 6;
  int b = blockIdx.x & 63;
  const int* cnt = arr ? cntV : cntE;
  int n = arr ? N : M;
  int chunk = (((n + SNB - 1) / SNB) + 3) & ~3;
  int lo = b * chunk, hi = min(lo + chunk, n);
  int s = 0;
  for (int i = lo + (int)threadIdx.x; i < hi; i += 256) s += cnt[i];
  #pragma unroll
  for (int o = 32; o; o >>= 1) s += __shfl_down(s, o);
  __shared__ int sh[4];
  if ((threadIdx.x & 63) == 0) sh[threadIdx.x >> 6] = s;
  __syncthreads();
  if (threadIdx.x == 0) bsum[blockIdx.x] = sh[0] + sh[1] + sh[2] + sh[3];
}

// Phase 2: scan the 128 block sums (wave 0 = E, wave 1 = V); write totals.
__global__ __launch_bounds__(128) void k_bscan(const int* __restrict__ bsum,
                                               int* __restrict__ bpre,
                                               int* __restrict__ offsE, int* __restrict__ offsV,
                                               int M, int N) {
  int t = threadIdx.x;
  int lane = t & 63;
  int v = bsum[t];
  int inc = wave_incl_scan(v, lane);
  bpre[t] = inc - v;
  if (lane == 63) {
    if (t < 64) offsE[M] = inc;
    else        offsV[N] = inc;
  }
}

// Phase 3: per-chunk exclusive scan + global base, write offs & cursor (int4).
__global__ __launch_bounds__(256) void k_woffs(const int* __restrict__ cntE,
                                               const int* __restrict__ cntV,
                                               const int* __restrict__ bpre,
                                               int* __restrict__ offsE, int* __restrict__ curE,
                                               int* __restrict__ offsV, int* __restrict__ curV,
                                               int M, int N) {
  int arr = blockIdx.x >> 6;
  int b = blockIdx.x & 63;
  const int* cnt = arr ? cntV : cntE;
  int* offs = arr ? offsV : offsE;
  int* cur  = arr ? curV  : curE;
  int n = arr ? N : M;
  int chunk = (((n + SNB - 1) / SNB) + 3) & ~3;
  int lo = b * chunk, hi = min(lo + chunk, n);
  if (lo >= n) return;
  int base = bpre[blockIdx.x];

  int idx = lo + (int)threadIdx.x * 4;
  int c0 = 0, c1 = 0, c2 = 0, c3 = 0;
  if (idx + 3 < hi) {
    int4 c = *reinterpret_cast<const int4*>(cnt + idx);
    c0 = c.x; c1 = c.y; c2 = c.z; c3 = c.w;
  } else if (idx < hi) {
    c0 = cnt[idx];
    if (idx + 1 < hi) c1 = cnt[idx + 1];
    if (idx + 2 < hi) c2 = cnt[idx + 2];
  }
  int tsum = c0 + c1 + c2 + c3;
  int lane = threadIdx.x & 63, wid = threadIdx.x >> 6;
  int winc = wave_incl_scan(tsum, lane);
  __shared__ int wtot[4];
  if (lane == 63) wtot[wid] = winc;
  __syncthreads();
  int wbase = 0;
  #pragma unroll
  for (int q = 0; q < 4; ++q) wbase += (q < wid) ? wtot[q] : 0;
  int excl = base + wbase + winc - tsum;
  int o0 = excl, o1 = o0 + c0, o2 = o1 + c1, o3 = o2 + c2;
  if (idx + 3 < hi) {
    *reinterpret_cast<int4*>(offs + idx) = make_int4(o0, o1, o2, o3);
    *reinterpret_cast<int4*>(cur + idx)  = make_int4(o0, o1, o2, o3);
  } else if (idx < hi) {
    offs[idx] = o0; cur[idx] = o0;
    if (idx + 1 < hi) { offs[idx + 1] = o1; cur[idx + 1] = o1; }
    if (idx + 2 < hi) { offs[idx + 2] = o2; cur[idx + 2] = o2; }
  }
}

// ---------------- fill: simple ushort scatter (proven passing in R9) ----------------

__global__ void k_fill(const int* __restrict__ vertex, const int* __restrict__ edges,
                       int* __restrict__ curE, int* __restrict__ curV,
                       ushort_t* __restrict__ incEv, ushort_t* __restrict__ incVe, int nnz) {
  int i = blockIdx.x * blockDim.x + threadIdx.x;
  if (i < nnz) {
    int v = vertex[i], e = edges[i];
    int pe = atomicAdd(&curE[e], 1);
    incEv[pe] = (ushort_t)v;
    int pv = atomicAdd(&curV[v], 1);
    incVe[pv] = (ushort_t)e;
  }
}

// ---------------- hop 1: mean-aggregate vertices into edges ----------------
// Pair-gather (2 halves x 32 lanes, 16B/lane -> 1KB/instr), 4-pair unroll + tail.
// (proven passing in R8)

__global__ void k_hop1(const ushort_t* __restrict__ Xbf, const float* __restrict__ degE,
                       const int* __restrict__ offsE, const ushort_t* __restrict__ incEv,
                       ushort_t* __restrict__ Xe, int M) {
  int gw = (blockIdx.x * blockDim.x + threadIdx.x) >> 6;
  int lane = threadIdx.x & 63;
  if (gw >= M) return;
  int half = lane >> 5, sub = lane & 31;
  int s = offsE[gw], t = offsE[gw + 1];
  float acc[8] = {0.f, 0.f, 0.f, 0.f, 0.f, 0.f, 0.f, 0.f};
  const ushort_t* rowbase = Xbf + sub * 8;
  int k = s;
  for (; k + 8 <= t; k += 8) {
    int4 x[4];
    #pragma unroll
    for (int p = 0; p < 4; ++p) {
      int lo = incEv[k + 2 * p], hi = incEv[k + 2 * p + 1];
      int v = half ? hi : lo;
      x[p] = *reinterpret_cast<const int4*>(rowbase + (size_t)v * DD);
    }
    #pragma unroll
    for (int p = 0; p < 4; ++p) addbf8(acc, x[p]);
  }
  for (; k < t; k += 2) {
    int idx = k + half;
    if (idx < t) {
      int v = incEv[idx];
      int4 x = *reinterpret_cast<const int4*>(rowbase + (size_t)v * DD);
      addbf8(acc, x);
    }
  }
  #pragma unroll
  for (int j = 0; j < 8; ++j) acc[j] += __shfl_xor(acc[j], 32);
  float scale = degE[gw] / fmaxf((float)(t - s), 1.0f);
  float b0 = half ? acc[4] : acc[0];
  float b1 = half ? acc[5] : acc[1];
  float b2 = half ? acc[6] : acc[2];
  float b3 = half ? acc[7] : acc[3];
  ushort4 r;
  r.x = f2bf(b0 * scale); r.y = f2bf(b1 * scale);
  r.z = f2bf(b2 * scale); r.w = f2bf(b3 * scale);
  *reinterpret_cast<ushort4*>(Xe + (size_t)gw * DD + sub * 8 + half * 4) = r;
}

// ---------------- hop 2: sum-aggregate edges into vertices + norm + alpha-mix ----
// (proven passing in R8)

__global__ void k_hop2(const ushort_t* __restrict__ Xe, const float* __restrict__ X0,
                       const float* __restrict__ degV, const int* __restrict__ offsV,
                       const ushort_t* __restrict__ incVe, const float* __restrict__ alpha_p,
                       float* __restrict__ Xi, int N) {
  int gw = (blockIdx.x * blockDim.x + threadIdx.x) >> 6;
  int lane = threadIdx.x & 63;
  if (gw >= N) return;
  int half = lane >> 5, sub = lane & 31;
  int s = offsV[gw], t = offsV[gw + 1];
  float acc[8] = {0.f, 0.f, 0.f, 0.f, 0.f, 0.f, 0.f, 0.f};
  const ushort_t* rowbase = Xe + sub * 8;
  int k = s;
  for (; k + 8 <= t; k += 8) {
    int4 x[4];
    #pragma unroll
    for (int p = 0; p < 4; ++p) {
      int lo = incVe[k + 2 * p], hi = incVe[k + 2 * p + 1];
      int e = half ? hi : lo;
      x[p] = *reinterpret_cast<const int4*>(rowbase + (size_t)e * DD);
    }
    #pragma unroll
    for (int p = 0; p < 4; ++p) addbf8(acc, x[p]);
  }
  for (; k < t; k += 2) {
    int idx = k + half;
    if (idx < t) {
      int e = incVe[idx];
      int4 x = *reinterpret_cast<const int4*>(rowbase + (size_t)e * DD);
      addbf8(acc, x);
    }
  }
  #pragma unroll
  for (int j = 0; j < 8; ++j) acc[j] += __shfl_xor(acc[j], 32);
  float dv = degV[gw];
  float b0 = (half ? acc[4] : acc[0]) * dv;
  float b1 = (half ? acc[5] : acc[1]) * dv;
  float b2 = (half ? acc[6] : acc[2]) * dv;
  float b3 = (half ? acc[7] : acc[3]) * dv;
  float ss = b0 * b0 + b1 * b1 + b2 * b2 + b3 * b3;
  #pragma unroll
  for (int o = 1; o < 64; o <<= 1) ss += __shfl_xor(ss, o);
  float norm = sqrtf(ss);
  float scl = (norm > 0.f) ? (1.0f / norm) : 0.f;
  float a = alpha_p[0];
  float oma = 1.0f - a;
  int f0 = sub * 8 + half * 4;
  float4 x0 = *reinterpret_cast<const float4*>(X0 + (size_t)gw * DD + f0);
  float4 r;
  r.x = oma * (b0 * scl) + a * x0.x;
  r.y = oma * (b1 * scl) + a * x0.y;
  r.z = oma * (b2 * scl) + a * x0.z;
  r.w = oma * (b3 * scl) + a * x0.w;
  *reinterpret_cast<float4*>(Xi + (size_t)gw * DD + f0) = r;
}

// ---------------- final: out = (1-beta)*Xi + beta*(Xi @ W), bf16 MFMA, in-place ----
// block = 128 rows x 256 cols (owns its rows exclusively -> in-place safe),
// 512 threads = 8 waves (2 row-waves x 4 col-waves), wave tile 64x64, acc[4][4].
// (proven passing in R7/R9)

__global__ __launch_bounds__(512, 4) void k_gemm_mfma(float* XiOut,
                                                      const ushort_t* __restrict__ Wt,
                                                      const float* __restrict__ beta_p,
                                                      int nrows) {
  __shared__ ushort_t A_lds[128][36];    // 9.2 KB
  __shared__ ushort_t B_lds[256][36];    // 18.4 KB
  const int tid = threadIdx.x;
  const int lane = tid & 63;
  const int wid = tid >> 6;              // 0..7
  const int wr = wid >> 2;               // 0..1 (row wave)
  const int wc = wid & 3;                // 0..3 (col wave)
  const int l15 = lane & 15;
  const int l4  = lane >> 4;             // 0..3
  const int row0 = blockIdx.x * 128;

  const int t2   = tid & 1;              // which 16-k half of the 32-k tile
  const int arow = tid >> 1;             // 0..255: A row (0..127 used) / B col

  f32x4 acc[4][4];
  #pragma unroll
  for (int m = 0; m < 4; ++m)
    #pragma unroll
    for (int n = 0; n < 4; ++n) acc[m][n] = (f32x4){0.f, 0.f, 0.f, 0.f};

  for (int k0 = 0; k0 < 256; k0 += 32) {
    // ---- stage A: 128 rows x 32 k, f32 -> bf16. thread owns 16 k of one row.
    if (arow < 128) {
      int grow = row0 + arow;
      float4 v0 = make_float4(0.f, 0.f, 0.f, 0.f), v1 = v0, v2 = v0, v3 = v0;
      if (grow < nrows) {
        const float* src = XiOut + (size_t)grow * 256 + k0 + t2 * 16;
        v0 = *reinterpret_cast<const float4*>(src + 0);
        v1 = *reinterpret_cast<const float4*>(src + 4);
        v2 = *reinterpret_cast<const float4*>(src + 8);
        v3 = *reinterpret_cast<const float4*>(src + 12);
      }
      uint4 pk0, pk1;
      pk0.x = (uint32_t)f2bf(v0.x) | ((uint32_t)f2bf(v0.y) << 16);
      pk0.y = (uint32_t)f2bf(v0.z) | ((uint32_t)f2bf(v0.w) << 16);
      pk0.z = (uint32_t)f2bf(v1.x) | ((uint32_t)f2bf(v1.y) << 16);
      pk0.w = (uint32_t)f2bf(v1.z) | ((uint32_t)f2bf(v1.w) << 16);
      pk1.x = (uint32_t)f2bf(v2.x) | ((uint32_t)f2bf(v2.y) << 16);
      pk1.y = (uint32_t)f2bf(v2.z) | ((uint32_t)f2bf(v2.w) << 16);
      pk1.z = (uint32_t)f2bf(v3.x) | ((uint32_t)f2bf(v3.y) << 16);
      pk1.w = (uint32_t)f2bf(v3.z) | ((uint32_t)f2bf(v3.w) << 16);
      *reinterpret_cast<uint4*>(&A_lds[arow][t2 * 16 + 0]) = pk0;
      *reinterpret_cast<uint4*>(&A_lds[arow][t2 * 16 + 8]) = pk1;
    }
    // ---- stage B: 256 cols x 32 k (already bf16). thread owns 16 k of one col.
    {
      const ushort_t* src = Wt + (size_t)arow * 256 + k0 + t2 * 16;
      int4 w0 = *reinterpret_cast<const int4*>(src + 0);
      int4 w1 = *reinterpret_cast<const int4*>(src + 8);
      *reinterpret_cast<int4*>(&B_lds[arow][t2 * 16 + 0]) = w0;
      *reinterpret_cast<int4*>(&B_lds[arow][t2 * 16 + 8]) = w1;
    }
    __syncthreads();
    short8v a[4], b[4];
    #pragma unroll
    for (int m = 0; m < 4; ++m)
      a[m] = *reinterpret_cast<const short8v*>(&A_lds[wr * 64 + m * 16 + l15][l4 * 8]);
    #pragma unroll
    for (int n = 0; n < 4; ++n)
      b[n] = *reinterpret_cast<const short8v*>(&B_lds[wc * 64 + n * 16 + l15][l4 * 8]);
    #pragma unroll
    for (int m = 0; m < 4; ++m)
      #pragma unroll
      for (int n = 0; n < 4; ++n)
        acc[m][n] = __builtin_amdgcn_mfma_f32_16x16x32_bf16(a[m], b[n], acc[m][n], 0, 0, 0);
    __syncthreads();
  }

  // epilogue: out = (1-b)*Xi + b*acc  (C/D: col = lane&15, row = (lane>>4)*4 + j)
  float b = beta_p[0], ob = 1.0f - b;
  int rb0 = row0 + wr * 64;
  int cb0 = wc * 64;
  #pragma unroll
  for (int m = 0; m < 4; ++m) {
    #pragma unroll
    for (int j = 0; j < 4; ++j) {
      int r = rb0 + m * 16 + l4 * 4 + j;
      if (r < nrows) {
        #pragma unroll
        for (int n = 0; n < 4; ++n) {
          size_t idx = (size_t)r * 256 + cb0 + n * 16 + l15;
          float xi = XiOut[idx];
          XiOut[idx] = ob * xi + b * acc[m][n][j];
        }
      }
    }
  }
}

// ---------------- launch ----------------

extern "C" void kernel_launch(void* const* d_in, const int* in_sizes, int n_in,
                              void* d_out, int out_size, void* d_ws, size_t ws_size,
                              hipStream_t stream) {
  const float* X     = (const float*)d_in[0];
  const float* X0    = (const float*)d_in[1];
  const float* W     = (const float*)d_in[2];
  const float* degV  = (const float*)d_in[3];
  const float* degE  = (const float*)d_in[4];
  const int*   vertex= (const int*)d_in[5];
  const int*   edges = (const int*)d_in[6];
  const float* alpha = (const float*)d_in[7];
  const float* beta  = (const float*)d_in[8];

  const int N   = in_sizes[3];   // degV has N elements
  const int M   = in_sizes[4];   // degE has M elements
  const int NNZ = in_sizes[5];

  auto r4 = [](int x) { return (x + 3) & ~3; };
  const int Mr = r4(M), Nr = r4(N);

  int* w = (int*)d_ws;
  int* cntE  = w; w += Mr;
  int* cntV  = w; w += Nr;        // contiguous with cntE for one memset
  int* offsE = w; w += r4(M + 1);
  int* offsV = w; w += r4(N + 1);
  int* curE  = w; w += Mr;
  int* curV  = w; w += Nr;
  int* bsum  = w; w += 128;
  int* bpre  = w; w += 128;
  ushort_t* incEv16 = (ushort_t*)w; w += (NNZ + 1) / 2;
  ushort_t* incVe16 = (ushort_t*)w; w += (NNZ + 1) / 2;
  uintptr_t p = (uintptr_t)w;
  p = (p + 15) & ~(uintptr_t)15;
  ushort_t* Wt = (ushort_t*)p;           // 256*256 bf16 = 128 KB
  p += (size_t)256 * 256 * sizeof(ushort_t);
  ushort_t* Xe = (ushort_t*)p;           // (M+1)*256 bf16 = 10.24 MB (+1 zero row)
  // total ws ~= 12.8 MB << proven-safe 24.5 MB footprint.

  float*    Xi  = (float*)d_out;         // N*256 f32 (hop2 output, GEMM in-place)
  ushort_t* Xbf = (ushort_t*)d_out;      // (N+1)*256 bf16 scratch inside d_out:
                                         // written by prep, read by hop1, then
                                         // d_out is overwritten by hop2 + gemm.

  hipMemsetAsync(cntE, 0, (size_t)(Mr + Nr) * sizeof(int), stream);

  int nb = (NNZ + 255) / 256;
  int xb = (N * (DD / 4) + 255) / 256;
  k_prep<<<256 + xb + nb, 256, 0, stream>>>(W, Wt, Xe + (size_t)M * DD,
                                            Xbf + (size_t)N * DD, X, Xbf, N * (DD / 4),
                                            vertex, edges, cntV, cntE, NNZ, xb);
  k_bsum <<<2 * SNB, 256, 0, stream>>>(cntE, cntV, bsum, M, N);
  k_bscan<<<1, 128, 0, stream>>>(bsum, bpre, offsE, offsV, M, N);
  k_woffs<<<2 * SNB, 256, 0, stream>>>(cntE, cntV, bpre, offsE, curE, offsV, curV, M, N);
  k_fill <<<nb, 256, 0, stream>>>(vertex, edges, curE, curV, incEv16, incVe16, NNZ);

  k_hop1<<<(M + 3) / 4, 256, 0, stream>>>(Xbf, degE, offsE, incEv16, Xe, M);
  k_hop2<<<(N + 3) / 4, 256, 0, stream>>>(Xe, X0, degV, offsV, incVe16, alpha, Xi, N);
  k_gemm_mfma<<<(N + 127) / 128, 512, 0, stream>>>(Xi, Wt, beta, N);
}

// Round 13
// 191.629 us; speedup vs baseline: 1.1145x; 1.0486x over previous
//
#include <hip/hip_runtime.h>
#include <cstdint>

static constexpr int DD = 256;   // feature dim (fixed by problem)
static constexpr int SNB = 64;   // scan blocks per array

typedef unsigned short ushort_t;
typedef __attribute__((ext_vector_type(8))) short short8v;   // 8 bf16 (4 VGPRs)
typedef __attribute__((ext_vector_type(4))) float f32x4;

static __device__ inline ushort_t f2bf(float f) {     // RNE f32->bf16 (no NaN in data)
  uint32_t u = __builtin_bit_cast(uint32_t, f);
  uint32_t r = (u + 0x7fffu + ((u >> 16) & 1u)) >> 16;
  return (ushort_t)r;
}
static __device__ inline float bf2f(ushort_t u) {
  return __builtin_bit_cast(float, (uint32_t)u << 16);
}
// unpack int4 (8 packed bf16) and accumulate into a[0..7] (static indices only)
static __device__ inline void addbf8(float* a, int4 x) {
  uint32_t ux = (uint32_t)x.x, uy = (uint32_t)x.y;
  uint32_t uz = (uint32_t)x.z, uw = (uint32_t)x.w;
  a[0] += __builtin_bit_cast(float, ux << 16);
  a[1] += __builtin_bit_cast(float, ux & 0xFFFF0000u);
  a[2] += __builtin_bit_cast(float, uy << 16);
  a[3] += __builtin_bit_cast(float, uy & 0xFFFF0000u);
  a[4] += __builtin_bit_cast(float, uz << 16);
  a[5] += __builtin_bit_cast(float, uz & 0xFFFF0000u);
  a[6] += __builtin_bit_cast(float, uw << 16);
  a[7] += __builtin_bit_cast(float, uw & 0xFFFF0000u);
}

// ---------------- count (critical path head; proven standalone R2-R9) ----------------

__global__ void k_count(const int* __restrict__ vertex, const int* __restrict__ edges,
                        int* __restrict__ cntV, int* __restrict__ cntE, int nnz) {
  int i = blockIdx.x * blockDim.x + threadIdx.x;
  if (i < nnz) {
    atomicAdd(&cntV[vertex[i]], 1);
    atomicAdd(&cntE[edges[i]], 1);
  }
}

__device__ inline int wave_incl_scan(int v, int lane) {
  #pragma unroll
  for (int o = 1; o < 64; o <<= 1) {
    int u = __shfl_up(v, o);
    if (lane >= o) v += u;
  }
  return v;
}

// Phase 1: per-chunk sums for both arrays. blocks 0..63 -> E, 64..127 -> V.
__global__ __launch_bounds__(256) void k_bsum(const int* __restrict__ cntE,
                                              const int* __restrict__ cntV,
                                              int* __restrict__ bsum, int M, int N) {
  int arr = blockIdx.x >> 6;
  int b = blockIdx.x & 63;
  const int* cnt = arr ? cntV : cntE;
  int n = arr ? N : M;
  int chunk = (((n + SNB - 1) / SNB) + 3) & ~3;
  int lo = b * chunk, hi = min(lo + chunk, n);
  int s = 0;
  for (int i = lo + (int)threadIdx.x; i < hi; i += 256) s += cnt[i];
  #pragma unroll
  for (int o = 32; o; o >>= 1) s += __shfl_down(s, o);
  __shared__ int sh[4];
  if ((threadIdx.x & 63) == 0) sh[threadIdx.x >> 6] = s;
  __syncthreads();
  if (threadIdx.x == 0) bsum[blockIdx.x] = sh[0] + sh[1] + sh[2] + sh[3];
}

// Phase 2 (merged bscan+woffs): each block re-scans the 128 chunk sums in-wave
// (wave 0 = E chunks, wave 1 = V chunks; scans are independent per array),
// then writes its chunk's offs & cursor (int4).
__global__ __launch_bounds__(256) void k_woffs2(const int* __restrict__ cntE,
                                                const int* __restrict__ cntV,
                                                const int* __restrict__ bsum,
                                                int* __restrict__ offsE, int* __restrict__ curE,
                                                int* __restrict__ offsV, int* __restrict__ curV,
                                                int M, int N) {
  __shared__ int sbpre[128];
  int tid = threadIdx.x;
  if (tid < 128) {
    int v = bsum[tid];
    int inc = wave_incl_scan(v, tid & 63);
    sbpre[tid] = inc - v;                       // exclusive prefix within array
    if (blockIdx.x == 0 && (tid & 63) == 63) {  // totals, written once
      if (tid < 64) offsE[M] = inc;
      else          offsV[N] = inc;
    }
  }
  __syncthreads();

  int arr = blockIdx.x >> 6;
  int b = blockIdx.x & 63;
  const int* cnt = arr ? cntV : cntE;
  int* offs = arr ? offsV : offsE;
  int* cur  = arr ? curV  : curE;
  int n = arr ? N : M;
  int chunk = (((n + SNB - 1) / SNB) + 3) & ~3;
  int lo = b * chunk, hi = min(lo + chunk, n);
  if (lo >= n) return;
  int base = sbpre[blockIdx.x];

  int idx = lo + (int)threadIdx.x * 4;
  int c0 = 0, c1 = 0, c2 = 0, c3 = 0;
  if (idx + 3 < hi) {
    int4 c = *reinterpret_cast<const int4*>(cnt + idx);
    c0 = c.x; c1 = c.y; c2 = c.z; c3 = c.w;
  } else if (idx < hi) {
    c0 = cnt[idx];
    if (idx + 1 < hi) c1 = cnt[idx + 1];
    if (idx + 2 < hi) c2 = cnt[idx + 2];
  }
  int tsum = c0 + c1 + c2 + c3;
  int lane = threadIdx.x & 63, wid = threadIdx.x >> 6;
  int winc = wave_incl_scan(tsum, lane);
  __shared__ int wtot[4];
  if (lane == 63) wtot[wid] = winc;
  __syncthreads();
  int wbase = 0;
  #pragma unroll
  for (int q = 0; q < 4; ++q) wbase += (q < wid) ? wtot[q] : 0;
  int excl = base + wbase + winc - tsum;
  int o0 = excl, o1 = o0 + c0, o2 = o1 + c1, o3 = o2 + c2;
  if (idx + 3 < hi) {
    *reinterpret_cast<int4*>(offs + idx) = make_int4(o0, o1, o2, o3);
    *reinterpret_cast<int4*>(cur + idx)  = make_int4(o0, o1, o2, o3);
  } else if (idx < hi) {
    offs[idx] = o0; cur[idx] = o0;
    if (idx + 1 < hi) { offs[idx + 1] = o1; cur[idx + 1] = o1; }
    if (idx + 2 < hi) { offs[idx + 2] = o2; cur[idx + 2] = o2; }
  }
}

// ---------------- fused fill + xcvt + W' convert ----------------
// blocks [0,nb): fill (ushort scatter; proven R9/R12).
// blocks [nb,nb+xb): X -> bf16 into d_out scratch (proven R10-R12).
// blocks [nb+xb, +256): Wt'[c][k] = bf16(beta*W[k][c] + (1-beta)*(k==c))
//   -- folds the residual mix into the GEMM: out = Xi @ W'.

__global__ void k_fillx(const int* __restrict__ vertex, const int* __restrict__ edges,
                        int* __restrict__ curE, int* __restrict__ curV,
                        ushort_t* __restrict__ incEv, ushort_t* __restrict__ incVe,
                        int nnz, int nb,
                        const float* __restrict__ X, ushort_t* __restrict__ Xbf,
                        int total4, int xb,
                        const float* __restrict__ W, const float* __restrict__ beta_p,
                        ushort_t* __restrict__ Wt) {
  int b = blockIdx.x;
  if (b < nb) {
    int i = b * 256 + (int)threadIdx.x;
    if (i < nnz) {
      int v = vertex[i], e = edges[i];
      int pe = atomicAdd(&curE[e], 1);
      incEv[pe] = (ushort_t)v;
      int pv = atomicAdd(&curV[v], 1);
      incVe[pv] = (ushort_t)e;
    }
  } else if (b < nb + xb) {
    int i = (b - nb) * 256 + (int)threadIdx.x;
    if (i < total4) {
      float4 v = reinterpret_cast<const float4*>(X)[i];
      ushort4 r;
      r.x = f2bf(v.x); r.y = f2bf(v.y); r.z = f2bf(v.z); r.w = f2bf(v.w);
      reinterpret_cast<ushort4*>(Xbf)[i] = r;
    }
  } else {
    int t = (b - nb - xb) * 256 + (int)threadIdx.x;   // [0, 65536)
    int k = t >> 8, c = t & 255;
    float beta = beta_p[0];
    float val = beta * W[t] + ((k == c) ? (1.0f - beta) : 0.0f);
    Wt[c * 256 + k] = f2bf(val);
  }
}

// ---------------- hop 1: mean-aggregate vertices into edges ----------------
// Pair-gather (2 halves x 32 lanes, 16B/lane -> 1KB/instr), 4-pair unroll + tail.
// (proven R8/R12)

__global__ void k_hop1(const ushort_t* __restrict__ Xbf, const float* __restrict__ degE,
                       const int* __restrict__ offsE, const ushort_t* __restrict__ incEv,
                       ushort_t* __restrict__ Xe, int M) {
  int gw = (blockIdx.x * blockDim.x + threadIdx.x) >> 6;
  int lane = threadIdx.x & 63;
  if (gw >= M) return;
  int half = lane >> 5, sub = lane & 31;
  int s = offsE[gw], t = offsE[gw + 1];
  float acc[8] = {0.f, 0.f, 0.f, 0.f, 0.f, 0.f, 0.f, 0.f};
  const ushort_t* rowbase = Xbf + sub * 8;
  int k = s;
  for (; k + 8 <= t; k += 8) {
    int4 x[4];
    #pragma unroll
    for (int p = 0; p < 4; ++p) {
      int lo = incEv[k + 2 * p], hi = incEv[k + 2 * p + 1];
      int v = half ? hi : lo;
      x[p] = *reinterpret_cast<const int4*>(rowbase + (size_t)v * DD);
    }
    #pragma unroll
    for (int p = 0; p < 4; ++p) addbf8(acc, x[p]);
  }
  for (; k < t; k += 2) {
    int idx = k + half;
    if (idx < t) {
      int v = incEv[idx];
      int4 x = *reinterpret_cast<const int4*>(rowbase + (size_t)v * DD);
      addbf8(acc, x);
    }
  }
  #pragma unroll
  for (int j = 0; j < 8; ++j) acc[j] += __shfl_xor(acc[j], 32);
  float scale = degE[gw] / fmaxf((float)(t - s), 1.0f);
  float b0 = half ? acc[4] : acc[0];
  float b1 = half ? acc[5] : acc[1];
  float b2 = half ? acc[6] : acc[2];
  float b3 = half ? acc[7] : acc[3];
  ushort4 r;
  r.x = f2bf(b0 * scale); r.y = f2bf(b1 * scale);
  r.z = f2bf(b2 * scale); r.w = f2bf(b3 * scale);
  *reinterpret_cast<ushort4*>(Xe + (size_t)gw * DD + sub * 8 + half * 4) = r;
}

// ---------------- hop 2: sum-aggregate edges into vertices + norm + alpha-mix ----
// (proven R8/R12)

__global__ void k_hop2(const ushort_t* __restrict__ Xe, const float* __restrict__ X0,
                       const float* __restrict__ degV, const int* __restrict__ offsV,
                       const ushort_t* __restrict__ incVe, const float* __restrict__ alpha_p,
                       float* __restrict__ Xi, int N) {
  int gw = (blockIdx.x * blockDim.x + threadIdx.x) >> 6;
  int lane = threadIdx.x & 63;
  if (gw >= N) return;
  int half = lane >> 5, sub = lane & 31;
  int s = offsV[gw], t = offsV[gw + 1];
  float acc[8] = {0.f, 0.f, 0.f, 0.f, 0.f, 0.f, 0.f, 0.f};
  const ushort_t* rowbase = Xe + sub * 8;
  int k = s;
  for (; k + 8 <= t; k += 8) {
    int4 x[4];
    #pragma unroll
    for (int p = 0; p < 4; ++p) {
      int lo = incVe[k + 2 * p], hi = incVe[k + 2 * p + 1];
      int e = half ? hi : lo;
      x[p] = *reinterpret_cast<const int4*>(rowbase + (size_t)e * DD);
    }
    #pragma unroll
    for (int p = 0; p < 4; ++p) addbf8(acc, x[p]);
  }
  for (; k < t; k += 2) {
    int idx = k + half;
    if (idx < t) {
      int e = incVe[idx];
      int4 x = *reinterpret_cast<const int4*>(rowbase + (size_t)e * DD);
      addbf8(acc, x);
    }
  }
  #pragma unroll
  for (int j = 0; j < 8; ++j) acc[j] += __shfl_xor(acc[j], 32);
  float dv = degV[gw];
  float b0 = (half ? acc[4] : acc[0]) * dv;
  float b1 = (half ? acc[5] : acc[1]) * dv;
  float b2 = (half ? acc[6] : acc[2]) * dv;
  float b3 = (half ? acc[7] : acc[3]) * dv;
  float ss = b0 * b0 + b1 * b1 + b2 * b2 + b3 * b3;
  #pragma unroll
  for (int o = 1; o < 64; o <<= 1) ss += __shfl_xor(ss, o);
  float norm = sqrtf(ss);
  float scl = (norm > 0.f) ? (1.0f / norm) : 0.f;
  float a = alpha_p[0];
  float oma = 1.0f - a;
  int f0 = sub * 8 + half * 4;
  float4 x0 = *reinterpret_cast<const float4*>(X0 + (size_t)gw * DD + f0);
  float4 r;
  r.x = oma * (b0 * scl) + a * x0.x;
  r.y = oma * (b1 * scl) + a * x0.y;
  r.z = oma * (b2 * scl) + a * x0.z;
  r.w = oma * (b3 * scl) + a * x0.w;
  *reinterpret_cast<float4*>(Xi + (size_t)gw * DD + f0) = r;
}

// ---------------- final: out = Xi @ W'  (W' = (1-beta)I + beta*W, pre-folded) ----
// block = 128 rows x 256 cols (owns rows exclusively -> in-place safe),
// 512 threads = 8 waves (2 row x 4 col), wave tile 64x64, acc[4][4].
// No epilogue re-read: residual mix is folded into W'.

__global__ __launch_bounds__(512, 4) void k_gemm_mfma(float* XiOut,
                                                      const ushort_t* __restrict__ Wt,
                                                      int nrows) {
  __shared__ ushort_t A_lds[128][36];    // 9.2 KB
  __shared__ ushort_t B_lds[256][36];    // 18.4 KB
  const int tid = threadIdx.x;
  const int lane = tid & 63;
  const int wid = tid >> 6;              // 0..7
  const int wr = wid >> 2;               // 0..1 (row wave)
  const int wc = wid & 3;                // 0..3 (col wave)
  const int l15 = lane & 15;
  const int l4  = lane >> 4;             // 0..3
  const int row0 = blockIdx.x * 128;

  const int t2   = tid & 1;              // which 16-k half of the 32-k tile
  const int arow = tid >> 1;             // 0..255: A row (0..127 used) / B col

  f32x4 acc[4][4];
  #pragma unroll
  for (int m = 0; m < 4; ++m)
    #pragma unroll
    for (int n = 0; n < 4; ++n) acc[m][n] = (f32x4){0.f, 0.f, 0.f, 0.f};

  for (int k0 = 0; k0 < 256; k0 += 32) {
    // ---- stage A: 128 rows x 32 k, f32 -> bf16. thread owns 16 k of one row.
    if (arow < 128) {
      int grow = row0 + arow;
      float4 v0 = make_float4(0.f, 0.f, 0.f, 0.f), v1 = v0, v2 = v0, v3 = v0;
      if (grow < nrows) {
        const float* src = XiOut + (size_t)grow * 256 + k0 + t2 * 16;
        v0 = *reinterpret_cast<const float4*>(src + 0);
        v1 = *reinterpret_cast<const float4*>(src + 4);
        v2 = *reinterpret_cast<const float4*>(src + 8);
        v3 = *reinterpret_cast<const float4*>(src + 12);
      }
      uint4 pk0, pk1;
      pk0.x = (uint32_t)f2bf(v0.x) | ((uint32_t)f2bf(v0.y) << 16);
      pk0.y = (uint32_t)f2bf(v0.z) | ((uint32_t)f2bf(v0.w) << 16);
      pk0.z = (uint32_t)f2bf(v1.x) | ((uint32_t)f2bf(v1.y) << 16);
      pk0.w = (uint32_t)f2bf(v1.z) | ((uint32_t)f2bf(v1.w) << 16);
      pk1.x = (uint32_t)f2bf(v2.x) | ((uint32_t)f2bf(v2.y) << 16);
      pk1.y = (uint32_t)f2bf(v2.z) | ((uint32_t)f2bf(v2.w) << 16);
      pk1.z = (uint32_t)f2bf(v3.x) | ((uint32_t)f2bf(v3.y) << 16);
      pk1.w = (uint32_t)f2bf(v3.z) | ((uint32_t)f2bf(v3.w) << 16);
      *reinterpret_cast<uint4*>(&A_lds[arow][t2 * 16 + 0]) = pk0;
      *reinterpret_cast<uint4*>(&A_lds[arow][t2 * 16 + 8]) = pk1;
    }
    // ---- stage B: 256 cols x 32 k (already bf16). thread owns 16 k of one col.
    {
      const ushort_t* src = Wt + (size_t)arow * 256 + k0 + t2 * 16;
      int4 w0 = *reinterpret_cast<const int4*>(src + 0);
      int4 w1 = *reinterpret_cast<const int4*>(src + 8);
      *reinterpret_cast<int4*>(&B_lds[arow][t2 * 16 + 0]) = w0;
      *reinterpret_cast<int4*>(&B_lds[arow][t2 * 16 + 8]) = w1;
    }
    __syncthreads();
    short8v a[4], b[4];
    #pragma unroll
    for (int m = 0; m < 4; ++m)
      a[m] = *reinterpret_cast<const short8v*>(&A_lds[wr * 64 + m * 16 + l15][l4 * 8]);
    #pragma unroll
    for (int n = 0; n < 4; ++n)
      b[n] = *reinterpret_cast<const short8v*>(&B_lds[wc * 64 + n * 16 + l15][l4 * 8]);
    #pragma unroll
    for (int m = 0; m < 4; ++m)
      #pragma unroll
      for (int n = 0; n < 4; ++n)
        acc[m][n] = __builtin_amdgcn_mfma_f32_16x16x32_bf16(a[m], b[n], acc[m][n], 0, 0, 0);
    __syncthreads();
  }

  // epilogue: out = acc  (C/D: col = lane&15, row = (lane>>4)*4 + j)
  int rb0 = row0 + wr * 64;
  int cb0 = wc * 64;
  #pragma unroll
  for (int m = 0; m < 4; ++m) {
    #pragma unroll
    for (int j = 0; j < 4; ++j) {
      int r = rb0 + m * 16 + l4 * 4 + j;
      if (r < nrows) {
        #pragma unroll
        for (int n = 0; n < 4; ++n) {
          size_t idx = (size_t)r * 256 + cb0 + n * 16 + l15;
          XiOut[idx] = acc[m][n][j];
        }
      }
    }
  }
}

// ---------------- launch ----------------

extern "C" void kernel_launch(void* const* d_in, const int* in_sizes, int n_in,
                              void* d_out, int out_size, void* d_ws, size_t ws_size,
                              hipStream_t stream) {
  const float* X     = (const float*)d_in[0];
  const float* X0    = (const float*)d_in[1];
  const float* W     = (const float*)d_in[2];
  const float* degV  = (const float*)d_in[3];
  const float* degE  = (const float*)d_in[4];
  const int*   vertex= (const int*)d_in[5];
  const int*   edges = (const int*)d_in[6];
  const float* alpha = (const float*)d_in[7];
  const float* beta  = (const float*)d_in[8];

  const int N   = in_sizes[3];   // degV has N elements
  const int M   = in_sizes[4];   // degE has M elements
  const int NNZ = in_sizes[5];

  auto r4 = [](int x) { return (x + 3) & ~3; };
  const int Mr = r4(M), Nr = r4(N);

  int* w = (int*)d_ws;
  int* cntE  = w; w += Mr;
  int* cntV  = w; w += Nr;        // contiguous with cntE for one memset
  int* offsE = w; w += r4(M + 1);
  int* offsV = w; w += r4(N + 1);
  int* curE  = w; w += Mr;
  int* curV  = w; w += Nr;
  int* bsum  = w; w += 128;
  ushort_t* incEv16 = (ushort_t*)w; w += (NNZ + 1) / 2;
  ushort_t* incVe16 = (ushort_t*)w; w += (NNZ + 1) / 2;
  uintptr_t p = (uintptr_t)w;
  p = (p + 15) & ~(uintptr_t)15;
  ushort_t* Wt = (ushort_t*)p;           // 256*256 bf16 = 128 KB (holds W')
  p += (size_t)256 * 256 * sizeof(ushort_t);
  ushort_t* Xe = (ushort_t*)p;           // M*256 bf16 = 10.24 MB
  // total ws ~= 12.8 MB << proven-safe 24.5 MB footprint.

  float*    Xi  = (float*)d_out;         // N*256 f32 (hop2 output, GEMM in-place)
  ushort_t* Xbf = (ushort_t*)d_out;      // N*256 bf16 scratch inside d_out:
                                         // written by fillx, read by hop1, then
                                         // d_out is overwritten by hop2 + gemm.

  hipMemsetAsync(cntE, 0, (size_t)(Mr + Nr) * sizeof(int), stream);

  int nb = (NNZ + 255) / 256;
  int total4 = N * (DD / 4);
  int xb = (total4 + 255) / 256;
  k_count <<<nb, 256, 0, stream>>>(vertex, edges, cntV, cntE, NNZ);
  k_bsum  <<<2 * SNB, 256, 0, stream>>>(cntE, cntV, bsum, M, N);
  k_woffs2<<<2 * SNB, 256, 0, stream>>>(cntE, cntV, bsum, offsE, curE, offsV, curV, M, N);
  k_fillx <<<nb + xb + 256, 256, 0, stream>>>(vertex, edges, curE, curV,
                                              incEv16, incVe16, NNZ, nb,
                                              X, Xbf, total4, xb,
                                              W, beta, Wt);

  k_hop1<<<(M + 3) / 4, 256, 0, stream>>>(Xbf, degE, offsE, incEv16, Xe, M);
  k_hop2<<<(N + 3) / 4, 256, 0, stream>>>(Xe, X0, degV, offsV, incVe16, alpha, Xi, N);
  k_gemm_mfma<<<(N + 127) / 128, 512, 0, stream>>>(Xi, Wt, N);
}